// Round 2
// baseline (482.935 us; speedup 1.0000x reference)
//
#include <hip/hip_runtime.h>

// The reference computes `features` and `z` but deletes them; the returned
// tensor is x.reshape(...) == x. The op is the identity on x: a 302 MB
// device-to-device copy (604 MB total traffic).
//
// Measured composition of the 481.6 us baseline:
//   2 x 187 us  harness re-poison fills (fillBufferAligned, not ours)
//   ~107 us     our 1-float4/thread copy  (floor: 604 MB / 6.3 TB/s = 96 us)
//
// This version: 4 x 16B per thread at block-tile stride 256 (4 VMEM loads in
// flight per thread before the first dependent store) + nontemporal
// load/store so the two single-touch streams don't allocate/evict in L2/L3.
//
// NOTE: __builtin_nontemporal_* rejects HIP's float4 (it's a struct, not a
// clang vector). Use a native ext_vector_type(4) float instead — identical
// 16B codegen (global_load/store_dwordx4 nt).

typedef float f4_t __attribute__((ext_vector_type(4)));

__global__ __launch_bounds__(256) void copy_f4x4(const f4_t* __restrict__ src,
                                                 f4_t* __restrict__ dst,
                                                 int n4) {
    int base = blockIdx.x * 1024 + threadIdx.x;   // 1024 = 256 threads * 4 f4
    if (base + 768 < n4) {
        // Full tile: 4 perfectly-coalesced 16B/lane accesses, ILP=4.
        f4_t a = __builtin_nontemporal_load(src + base);
        f4_t b = __builtin_nontemporal_load(src + base + 256);
        f4_t c = __builtin_nontemporal_load(src + base + 512);
        f4_t d = __builtin_nontemporal_load(src + base + 768);
        __builtin_nontemporal_store(a, dst + base);
        __builtin_nontemporal_store(b, dst + base + 256);
        __builtin_nontemporal_store(c, dst + base + 512);
        __builtin_nontemporal_store(d, dst + base + 768);
    } else {
        // Tail (not hit for n4 = 18,874,368, which is 1024-aligned).
        for (int i = base; i < n4; i += 256) dst[i] = src[i];
    }
}

extern "C" void kernel_launch(void* const* d_in, const int* in_sizes, int n_in,
                              void* d_out, int out_size, void* d_ws, size_t ws_size,
                              hipStream_t stream) {
    (void)in_sizes; (void)n_in; (void)d_ws; (void)ws_size;
    const f4_t* x = (const f4_t*)d_in[0];
    f4_t* out = (f4_t*)d_out;
    int n4 = out_size / 4;                 // 18,874,368 float4s (302 MB)
    int blocks = (n4 + 1023) / 1024;       // 18,432 blocks, no tail
    copy_f4x4<<<blocks, 256, 0, stream>>>(x, out, n4);
}